// Round 2
// baseline (172.604 us; speedup 1.0000x reference)
//
#include <hip/hip_runtime.h>

#define BSZ 8
#define SEQ 512
#define HID 768
#define N1 128
#define N2 24
#define HS 64
#define HEADS 12
#define KC 64
#define MT 16
#define INFV 10000.0f

// Kernel 1: x = inputs@W1 + b1 (16-row tile), RoPE -> qw (row-major), kwT (d-major),
// bias = (x@W2 + b2)/2 -> biasT (c-major).
__global__ __launch_bounds__(256) void k1_proj(
    const float* __restrict__ inp, const float* __restrict__ W1,
    const float* __restrict__ b1, const float* __restrict__ W2,
    const float* __restrict__ b2, float* __restrict__ qw,
    float* __restrict__ kwT, float* __restrict__ biasT)
{
    __shared__ float As[KC][MT + 1];
    __shared__ float Bs[KC][N1];
    __shared__ float xs[MT][N1];

    const int tid = threadIdx.x;
    const int row0 = blockIdx.x * MT;   // global row in [0,4096)
    const int b = row0 / SEQ;
    const int m0 = row0 % SEQ;

    const int tx = tid & 31;   // col group (4 cols)
    const int ty = tid >> 5;   // row group (2 rows)

    float acc[2][4];
#pragma unroll
    for (int i = 0; i < 2; ++i)
#pragma unroll
        for (int j = 0; j < 4; ++j) acc[i][j] = 0.0f;

    for (int k0 = 0; k0 < HID; k0 += KC) {
#pragma unroll
        for (int i = 0; i < 4; ++i) {
            int idx = tid + i * 256;          // 0..1023
            int r = idx >> 6, kk = idx & 63;
            As[kk][r] = inp[(size_t)(row0 + r) * HID + k0 + kk];
        }
#pragma unroll
        for (int i = 0; i < 32; ++i) {
            int idx = tid + i * 256;          // 0..8191
            int kk = idx >> 7, c = idx & 127;
            Bs[kk][c] = W1[(size_t)(k0 + kk) * N1 + c];
        }
        __syncthreads();
        for (int kk = 0; kk < KC; ++kk) {
            float a0 = As[kk][ty * 2];
            float a1 = As[kk][ty * 2 + 1];
            float4 bv = *(const float4*)&Bs[kk][tx * 4];
            acc[0][0] = fmaf(a0, bv.x, acc[0][0]);
            acc[0][1] = fmaf(a0, bv.y, acc[0][1]);
            acc[0][2] = fmaf(a0, bv.z, acc[0][2]);
            acc[0][3] = fmaf(a0, bv.w, acc[0][3]);
            acc[1][0] = fmaf(a1, bv.x, acc[1][0]);
            acc[1][1] = fmaf(a1, bv.y, acc[1][1]);
            acc[1][2] = fmaf(a1, bv.z, acc[1][2]);
            acc[1][3] = fmaf(a1, bv.w, acc[1][3]);
        }
        __syncthreads();
    }

    {   // x tile -> LDS (+b1)
        float4 bb = *(const float4*)&b1[tx * 4];
#pragma unroll
        for (int i = 0; i < 2; ++i) {
            float4 v;
            v.x = acc[i][0] + bb.x; v.y = acc[i][1] + bb.y;
            v.z = acc[i][2] + bb.z; v.w = acc[i][3] + bb.w;
            *(float4*)&xs[ty * 2 + i][tx * 4] = v;
        }
    }
    __syncthreads();

    {   // RoPE: 16 rows x 16 lanes, 2 rotation-pairs each
        const int r = tid >> 4;
        const int l = tid & 15;
        const int m = m0 + r;
        const float C = 13.287712379549449f / 32.0f;   // log2(10000)/32
#pragma unroll
        for (int jj = 0; jj < 2; ++jj) {
            int j = l + jj * 16;                       // 0..31
            float invf = exp2f(-(float)j * C);         // 10000^(-j/32)
            float ang = (float)m * invf;
            float sv, cv;
            sincosf(ang, &sv, &cv);
            float4 xv = *(const float4*)&xs[r][4 * j]; // x[4j..4j+3]
            float rq0 = xv.x * cv - xv.z * sv;         // q pair = x[4j], x[4j+2]
            float rq1 = xv.x * sv + xv.z * cv;
            float rk0 = xv.y * cv - xv.w * sv;         // k pair = x[4j+1], x[4j+3]
            float rk1 = xv.y * sv + xv.w * cv;
            size_t qb = (size_t)(b * SEQ + m) * HS;
            qw[qb + 2 * j]     = rq0;
            qw[qb + 2 * j + 1] = rq1;
            kwT[(size_t)(b * HS + 2 * j)     * SEQ + m] = rk0;
            kwT[(size_t)(b * HS + 2 * j + 1) * SEQ + m] = rk1;
        }
    }

    // bias = (x@W2 + b2) * 0.5, stored c-major
#pragma unroll
    for (int pass = 0; pass < 2; ++pass) {
        int idx = tid + pass * 256;
        if (idx < MT * N2) {
            int r = idx / N2, c = idx - r * N2;
            float dot = b2[c];
#pragma unroll 4
            for (int k = 0; k < N1; ++k)
                dot = fmaf(xs[r][k], W2[k * N2 + c], dot);
            biasT[(size_t)(b * N2 + c) * SEQ + (m0 + r)] = dot * 0.5f;
        }
    }
}

// Kernel 2: per block = (b, 8 m-rows) x 512 n. 256 threads, 2 n's each -> float2 stores.
__global__ __launch_bounds__(256) void k2_out(
    const float* __restrict__ qw, const float* __restrict__ kwT,
    const float* __restrict__ biasT, const int* __restrict__ am,
    float* __restrict__ out)
{
    __shared__ float q_lds[8][HS];
    __shared__ float bo[8][HEADS];
    __shared__ int amm[8];

    const int tid = threadIdx.x;
    const int b = blockIdx.x >> 6;
    const int m0 = (blockIdx.x & 63) * 8;

#pragma unroll
    for (int i = 0; i < 2; ++i) {
        int idx = tid + i * 256;
        q_lds[idx >> 6][idx & 63] = qw[(size_t)(b * SEQ + m0) * HS + idx];
    }
    if (tid < 96) {
        int r = tid / 12, h = tid - r * 12;
        bo[r][h] = biasT[(size_t)(b * N2 + 2 * h + 1) * SEQ + m0 + r];
    }
    if (tid < 8) amm[tid] = am[b * SEQ + m0 + tid];
    __syncthreads();

    const int n0 = tid * 2;
    float qk0[8] = {0, 0, 0, 0, 0, 0, 0, 0};
    float qk1[8] = {0, 0, 0, 0, 0, 0, 0, 0};

#pragma unroll
    for (int dc = 0; dc < 2; ++dc) {
        float2 kn[32];
#pragma unroll
        for (int d = 0; d < 32; ++d)
            kn[d] = *(const float2*)&kwT[(size_t)(b * HS + dc * 32 + d) * SEQ + n0];
#pragma unroll
        for (int r = 0; r < 8; ++r) {
#pragma unroll
            for (int d4 = 0; d4 < 8; ++d4) {
                float4 qv = *(const float4*)&q_lds[r][dc * 32 + d4 * 4];
                qk0[r] = fmaf(qv.x, kn[d4 * 4 + 0].x, qk0[r]);
                qk0[r] = fmaf(qv.y, kn[d4 * 4 + 1].x, qk0[r]);
                qk0[r] = fmaf(qv.z, kn[d4 * 4 + 2].x, qk0[r]);
                qk0[r] = fmaf(qv.w, kn[d4 * 4 + 3].x, qk0[r]);
                qk1[r] = fmaf(qv.x, kn[d4 * 4 + 0].y, qk1[r]);
                qk1[r] = fmaf(qv.y, kn[d4 * 4 + 1].y, qk1[r]);
                qk1[r] = fmaf(qv.z, kn[d4 * 4 + 2].y, qk1[r]);
                qk1[r] = fmaf(qv.w, kn[d4 * 4 + 3].y, qk1[r]);
            }
        }
    }

    const int amn0 = am[b * SEQ + n0];
    const int amn1 = am[b * SEQ + n0 + 1];
    float pen0[8], pen1[8];
    float2 mo[8];
#pragma unroll
    for (int r = 0; r < 8; ++r) {
        int m = m0 + r;
        float msk0 = (1.0f - (float)(amn0 * amm[r])) * INFV;
        float msk1 = (1.0f - (float)(amn1 * amm[r])) * INFV;
        pen0[r] = msk0 + ((n0 < m) ? INFV : 0.0f);
        pen1[r] = msk1 + ((n0 + 1 < m) ? INFV : 0.0f);
        bool b0 = (amn0 * amm[r] != 1) || (n0 < m);
        bool b1m = (amn1 * amm[r] != 1) || (n0 + 1 < m);
        mo[r].x = b0 ? 1.0f : 0.0f;
        mo[r].y = b1m ? 1.0f : 0.0f;
    }

    float2 be[HEADS];
#pragma unroll
    for (int h = 0; h < HEADS; ++h)
        be[h] = *(const float2*)&biasT[(size_t)(b * N2 + 2 * h) * SEQ + n0];

    const size_t obase = (size_t)b * HEADS * SEQ * SEQ + n0;
#pragma unroll
    for (int h = 0; h < HEADS; ++h) {
#pragma unroll
        for (int r = 0; r < 8; ++r) {
            float2 v;
            v.x = fmaf(qk0[r], 0.125f, be[h].x + bo[r][h]) - pen0[r];
            v.y = fmaf(qk1[r], 0.125f, be[h].y + bo[r][h]) - pen1[r];
            *(float2*)&out[obase + ((size_t)h * SEQ + m0 + r) * SEQ] = v;
        }
    }
    const size_t mbase = (size_t)BSZ * HEADS * SEQ * SEQ
                       + ((size_t)b * SEQ + m0) * SEQ + n0;
#pragma unroll
    for (int r = 0; r < 8; ++r)
        *(float2*)&out[mbase + (size_t)r * SEQ] = mo[r];
}

extern "C" void kernel_launch(void* const* d_in, const int* in_sizes, int n_in,
                              void* d_out, int out_size, void* d_ws, size_t ws_size,
                              hipStream_t stream) {
    const float* inp = (const float*)d_in[0];
    const int*   am  = (const int*)d_in[1];
    const float* W1  = (const float*)d_in[2];
    const float* b1  = (const float*)d_in[3];
    const float* W2  = (const float*)d_in[4];
    const float* b2  = (const float*)d_in[5];

    float* ws    = (float*)d_ws;
    float* qw    = ws;                 // 8*512*64   = 262144 floats
    float* kwT   = ws + 262144;        // 8*64*512   = 262144 floats
    float* biasT = ws + 524288;        // 8*24*512   =  98304 floats (2.5 MB total)

    float* out = (float*)d_out;        // f32, per reference output dtype

    hipLaunchKernelGGL(k1_proj, dim3(4096 / MT), dim3(256), 0, stream,
                       inp, W1, b1, W2, b2, qw, kwT, biasT);
    hipLaunchKernelGGL(k2_out, dim3(4096 / 8), dim3(256), 0, stream,
                       qw, kwT, biasT, am, out);
}

// Round 3
// 78.386 us; speedup vs baseline: 2.2020x; 2.2020x over previous
//
#include <hip/hip_runtime.h>

#define BSZ 8
#define SEQ 512
#define HID 768
#define N1 128
#define N2 24
#define HS 64
#define HEADS 12
#define ROWS 8
#define INFV 10000.0f

// 32 FMAs: 8 k-steps for 2 rows x 2 cols, W = float2[8] of W1 cols (2c2, 2c2+1)
#define FMA8(W, K) do { \
    float4 x0 = *(const float4*)(a0p + (K));     \
    float4 x1 = *(const float4*)(a0p + (K) + 4); \
    float4 y0 = *(const float4*)(a1p + (K));     \
    float4 y1 = *(const float4*)(a1p + (K) + 4); \
    acc00 = fmaf(x0.x, W[0].x, acc00); acc01 = fmaf(x0.x, W[0].y, acc01); \
    acc10 = fmaf(y0.x, W[0].x, acc10); acc11 = fmaf(y0.x, W[0].y, acc11); \
    acc00 = fmaf(x0.y, W[1].x, acc00); acc01 = fmaf(x0.y, W[1].y, acc01); \
    acc10 = fmaf(y0.y, W[1].x, acc10); acc11 = fmaf(y0.y, W[1].y, acc11); \
    acc00 = fmaf(x0.z, W[2].x, acc00); acc01 = fmaf(x0.z, W[2].y, acc01); \
    acc10 = fmaf(y0.z, W[2].x, acc10); acc11 = fmaf(y0.z, W[2].y, acc11); \
    acc00 = fmaf(x0.w, W[3].x, acc00); acc01 = fmaf(x0.w, W[3].y, acc01); \
    acc10 = fmaf(y0.w, W[3].x, acc10); acc11 = fmaf(y0.w, W[3].y, acc11); \
    acc00 = fmaf(x1.x, W[4].x, acc00); acc01 = fmaf(x1.x, W[4].y, acc01); \
    acc10 = fmaf(y1.x, W[4].x, acc10); acc11 = fmaf(y1.x, W[4].y, acc11); \
    acc00 = fmaf(x1.y, W[5].x, acc00); acc01 = fmaf(x1.y, W[5].y, acc01); \
    acc10 = fmaf(y1.y, W[5].x, acc10); acc11 = fmaf(y1.y, W[5].y, acc11); \
    acc00 = fmaf(x1.z, W[6].x, acc00); acc01 = fmaf(x1.z, W[6].y, acc01); \
    acc10 = fmaf(y1.z, W[6].x, acc10); acc11 = fmaf(y1.z, W[6].y, acc11); \
    acc00 = fmaf(x1.w, W[7].x, acc00); acc01 = fmaf(x1.w, W[7].y, acc01); \
    acc10 = fmaf(y1.w, W[7].x, acc10); acc11 = fmaf(y1.w, W[7].y, acc11); \
} while (0)

// k1: 512 blocks x 256 thr, 8 rows/block. x = inp@W1+b1 (W1 from L2, dbuf regs),
// epilogue: RoPE -> qw + kwT (LDS transpose), bias=(x@W2+b2)/2 -> biasT.
__global__ __launch_bounds__(256) void k1_proj(
    const float* __restrict__ inp, const float* __restrict__ W1,
    const float* __restrict__ b1, const float* __restrict__ W2,
    const float* __restrict__ b2, float* __restrict__ qw,
    float* __restrict__ kwT, float* __restrict__ biasT)
{
    __shared__ float inpS[ROWS * HID];   // 24 KB; first 4 KB reused as xs[8][128]
    __shared__ float kT[HS][9];          // kwT transpose staging (+1 pad)

    const int tid = threadIdx.x;
    const int row0 = blockIdx.x * ROWS;
    const int b = row0 >> 9;
    const int m0 = row0 & 511;

    {   // stage inp tile (coalesced float4)
        const float4* src = (const float4*)(inp + (size_t)row0 * HID);
        float4* dst = (float4*)inpS;
#pragma unroll
        for (int i = 0; i < 6; ++i)
            dst[tid + i * 256] = src[tid + i * 256];
    }
    __syncthreads();

    const int c2 = tid & 63;   // col pair: cols 2c2, 2c2+1
    const int rg = tid >> 6;   // wave id: rows 2rg, 2rg+1 (wave-uniform)
    const float* a0p = inpS + (rg * 2) * HID;
    const float* a1p = a0p + HID;
    const float* wp = W1 + c2 * 2;

    float acc00 = 0.f, acc01 = 0.f, acc10 = 0.f, acc11 = 0.f;
    float2 wa[8], wb[8];
#pragma unroll
    for (int i = 0; i < 8; ++i) wa[i] = *(const float2*)(wp + (size_t)i * N1);

    for (int k0 = 0; k0 < HID; k0 += 16) {
#pragma unroll
        for (int i = 0; i < 8; ++i)
            wb[i] = *(const float2*)(wp + (size_t)(k0 + 8 + i) * N1);
        FMA8(wa, k0);
        if (k0 + 16 < HID) {
#pragma unroll
            for (int i = 0; i < 8; ++i)
                wa[i] = *(const float2*)(wp + (size_t)(k0 + 16 + i) * N1);
        }
        FMA8(wb, k0 + 8);
    }

    __syncthreads();             // everyone done reading inpS
    float* xs = inpS;            // overlay: xs[8][128]
    {
        float2 bb = *(const float2*)(b1 + c2 * 2);
        *(float2*)(xs + (rg * 2) * N1 + c2 * 2)     = make_float2(acc00 + bb.x, acc01 + bb.y);
        *(float2*)(xs + (rg * 2 + 1) * N1 + c2 * 2) = make_float2(acc10 + bb.x, acc11 + bb.y);
    }
    __syncthreads();

    {   // RoPE: thread = (row r, pair j)
        const int r = tid >> 5, j = tid & 31;
        const int m = m0 + r;
        const float C = 0.4152410118609203f;      // log2(10000)/32
        float invf = exp2f(-(float)j * C);        // 10000^(-j/32)
        float ang = (float)m * invf;
        float sv, cv;
        sincosf(ang, &sv, &cv);
        float4 xv = *(const float4*)(xs + r * N1 + 4 * j);
        float rq0 = xv.x * cv - xv.z * sv;        // q pair = x[4j], x[4j+2]
        float rq1 = xv.x * sv + xv.z * cv;
        float rk0 = xv.y * cv - xv.w * sv;        // k pair = x[4j+1], x[4j+3]
        float rk1 = xv.y * sv + xv.w * cv;
        *(float2*)(qw + (size_t)(b * SEQ + m) * HS + 2 * j) = make_float2(rq0, rq1);
        kT[2 * j][r]     = rk0;
        kT[2 * j + 1][r] = rk1;
    }

    // bias = (x@W2 + b2) * 0.5, c-major
    if (tid < ROWS * N2) {
        int r = tid / N2, c = tid - r * N2;
        const float* xr = xs + r * N1;
        float dot = b2[c];
#pragma unroll 8
        for (int k = 0; k < N1; ++k)
            dot = fmaf(xr[k], W2[k * N2 + c], dot);
        biasT[(size_t)(b * N2 + c) * SEQ + m0 + r] = dot * 0.5f;
    }
    __syncthreads();

    {   // kwT writeout (coalesced-ish float2 from LDS transpose)
        int d = tid >> 2, q = tid & 3;
        float2 v = *(const float2*)&kT[d][2 * q];
        *(float2*)(kwT + (size_t)(b * HS + d) * SEQ + m0 + 2 * q) = v;
    }
}

// Kernel 2: per block = (b, 8 m-rows) x 512 n. 256 threads, 2 n's each -> float2 stores.
__global__ __launch_bounds__(256) void k2_out(
    const float* __restrict__ qw, const float* __restrict__ kwT,
    const float* __restrict__ biasT, const int* __restrict__ am,
    float* __restrict__ out)
{
    __shared__ float q_lds[8][HS];
    __shared__ float bo[8][HEADS];
    __shared__ int amm[8];

    const int tid = threadIdx.x;
    const int b = blockIdx.x >> 6;
    const int m0 = (blockIdx.x & 63) * 8;

#pragma unroll
    for (int i = 0; i < 2; ++i) {
        int idx = tid + i * 256;
        q_lds[idx >> 6][idx & 63] = qw[(size_t)(b * SEQ + m0) * HS + idx];
    }
    if (tid < 96) {
        int r = tid / 12, h = tid - r * 12;
        bo[r][h] = biasT[(size_t)(b * N2 + 2 * h + 1) * SEQ + m0 + r];
    }
    if (tid < 8) amm[tid] = am[b * SEQ + m0 + tid];
    __syncthreads();

    const int n0 = tid * 2;
    float qk0[8] = {0, 0, 0, 0, 0, 0, 0, 0};
    float qk1[8] = {0, 0, 0, 0, 0, 0, 0, 0};

#pragma unroll
    for (int dc = 0; dc < 2; ++dc) {
        float2 kn[32];
#pragma unroll
        for (int d = 0; d < 32; ++d)
            kn[d] = *(const float2*)&kwT[(size_t)(b * HS + dc * 32 + d) * SEQ + n0];
#pragma unroll
        for (int r = 0; r < 8; ++r) {
#pragma unroll
            for (int d4 = 0; d4 < 8; ++d4) {
                float4 qv = *(const float4*)&q_lds[r][dc * 32 + d4 * 4];
                qk0[r] = fmaf(qv.x, kn[d4 * 4 + 0].x, qk0[r]);
                qk0[r] = fmaf(qv.y, kn[d4 * 4 + 1].x, qk0[r]);
                qk0[r] = fmaf(qv.z, kn[d4 * 4 + 2].x, qk0[r]);
                qk0[r] = fmaf(qv.w, kn[d4 * 4 + 3].x, qk0[r]);
                qk1[r] = fmaf(qv.x, kn[d4 * 4 + 0].y, qk1[r]);
                qk1[r] = fmaf(qv.y, kn[d4 * 4 + 1].y, qk1[r]);
                qk1[r] = fmaf(qv.z, kn[d4 * 4 + 2].y, qk1[r]);
                qk1[r] = fmaf(qv.w, kn[d4 * 4 + 3].y, qk1[r]);
            }
        }
    }

    const int amn0 = am[b * SEQ + n0];
    const int amn1 = am[b * SEQ + n0 + 1];
    float pen0[8], pen1[8];
    float2 mo[8];
#pragma unroll
    for (int r = 0; r < 8; ++r) {
        int m = m0 + r;
        float msk0 = (1.0f - (float)(amn0 * amm[r])) * INFV;
        float msk1 = (1.0f - (float)(amn1 * amm[r])) * INFV;
        pen0[r] = msk0 + ((n0 < m) ? INFV : 0.0f);
        pen1[r] = msk1 + ((n0 + 1 < m) ? INFV : 0.0f);
        bool b0 = (amn0 * amm[r] != 1) || (n0 < m);
        bool b1m = (amn1 * amm[r] != 1) || (n0 + 1 < m);
        mo[r].x = b0 ? 1.0f : 0.0f;
        mo[r].y = b1m ? 1.0f : 0.0f;
    }

    float2 be[HEADS];
#pragma unroll
    for (int h = 0; h < HEADS; ++h)
        be[h] = *(const float2*)&biasT[(size_t)(b * N2 + 2 * h) * SEQ + n0];

    const size_t obase = (size_t)b * HEADS * SEQ * SEQ + n0;
#pragma unroll
    for (int h = 0; h < HEADS; ++h) {
#pragma unroll
        for (int r = 0; r < 8; ++r) {
            float2 v;
            v.x = fmaf(qk0[r], 0.125f, be[h].x + bo[r][h]) - pen0[r];
            v.y = fmaf(qk1[r], 0.125f, be[h].y + bo[r][h]) - pen1[r];
            *(float2*)&out[obase + ((size_t)h * SEQ + m0 + r) * SEQ] = v;
        }
    }
    const size_t mbase = (size_t)BSZ * HEADS * SEQ * SEQ
                       + ((size_t)b * SEQ + m0) * SEQ + n0;
#pragma unroll
    for (int r = 0; r < 8; ++r)
        *(float2*)&out[mbase + (size_t)r * SEQ] = mo[r];
}

extern "C" void kernel_launch(void* const* d_in, const int* in_sizes, int n_in,
                              void* d_out, int out_size, void* d_ws, size_t ws_size,
                              hipStream_t stream) {
    const float* inp = (const float*)d_in[0];
    const int*   am  = (const int*)d_in[1];
    const float* W1  = (const float*)d_in[2];
    const float* b1  = (const float*)d_in[3];
    const float* W2  = (const float*)d_in[4];
    const float* b2  = (const float*)d_in[5];

    float* ws    = (float*)d_ws;
    float* qw    = ws;                 // 8*512*64 = 262144 floats
    float* kwT   = ws + 262144;        // 8*64*512 = 262144 floats
    float* biasT = ws + 524288;        // 8*24*512 =  98304 floats

    float* out = (float*)d_out;

    hipLaunchKernelGGL(k1_proj, dim3(4096 / ROWS), dim3(256), 0, stream,
                       inp, W1, b1, W2, b2, qw, kwT, biasT);
    hipLaunchKernelGGL(k2_out, dim3(4096 / 8), dim3(256), 0, stream,
                       qw, kwT, biasT, am, out);
}

// Round 4
// 77.229 us; speedup vs baseline: 2.2350x; 1.0150x over previous
//
#include <hip/hip_runtime.h>

#define BSZ 8
#define SEQ 512
#define HID 768
#define KHALF 384
#define N1 128
#define N2 24
#define HS 64
#define HEADS 12
#define ROWS 8
#define INFV 10000.0f

// 32 FMAs: 8 k-steps for 2 rows x 2 cols, W = float2[8] of W1 cols (2c2, 2c2+1)
#define FMA8(W, K) do { \
    float4 x0 = *(const float4*)(a0p + (K));     \
    float4 x1 = *(const float4*)(a0p + (K) + 4); \
    float4 y0 = *(const float4*)(a1p + (K));     \
    float4 y1 = *(const float4*)(a1p + (K) + 4); \
    acc00 = fmaf(x0.x, W[0].x, acc00); acc01 = fmaf(x0.x, W[0].y, acc01); \
    acc10 = fmaf(y0.x, W[0].x, acc10); acc11 = fmaf(y0.x, W[0].y, acc11); \
    acc00 = fmaf(x0.y, W[1].x, acc00); acc01 = fmaf(x0.y, W[1].y, acc01); \
    acc10 = fmaf(y0.y, W[1].x, acc10); acc11 = fmaf(y0.y, W[1].y, acc11); \
    acc00 = fmaf(x0.z, W[2].x, acc00); acc01 = fmaf(x0.z, W[2].y, acc01); \
    acc10 = fmaf(y0.z, W[2].x, acc10); acc11 = fmaf(y0.z, W[2].y, acc11); \
    acc00 = fmaf(x0.w, W[3].x, acc00); acc01 = fmaf(x0.w, W[3].y, acc01); \
    acc10 = fmaf(y0.w, W[3].x, acc10); acc11 = fmaf(y0.w, W[3].y, acc11); \
    acc00 = fmaf(x1.x, W[4].x, acc00); acc01 = fmaf(x1.x, W[4].y, acc01); \
    acc10 = fmaf(y1.x, W[4].x, acc10); acc11 = fmaf(y1.x, W[4].y, acc11); \
    acc00 = fmaf(x1.y, W[5].x, acc00); acc01 = fmaf(x1.y, W[5].y, acc01); \
    acc10 = fmaf(y1.y, W[5].x, acc10); acc11 = fmaf(y1.y, W[5].y, acc11); \
    acc00 = fmaf(x1.z, W[6].x, acc00); acc01 = fmaf(x1.z, W[6].y, acc01); \
    acc10 = fmaf(y1.z, W[6].x, acc10); acc11 = fmaf(y1.z, W[6].y, acc11); \
    acc00 = fmaf(x1.w, W[7].x, acc00); acc01 = fmaf(x1.w, W[7].y, acc01); \
    acc10 = fmaf(y1.w, W[7].x, acc10); acc11 = fmaf(y1.w, W[7].y, acc11); \
} while (0)

#define LOADW(W, KK) do { \
    _Pragma("unroll") \
    for (int _i = 0; _i < 8; ++_i) \
        W[_i] = *(const float2*)(wp + (size_t)((KK) + _i) * N1); \
} while (0)

// k1: 512 blocks x 512 thr. Waves 0-3: K half [0,384); waves 4-7: [384,768).
// Partial-sum reduce via LDS, then fused RoPE/bias/kwT epilogue.
__global__ __launch_bounds__(512, 4) void k1_proj(
    const float* __restrict__ inp, const float* __restrict__ W1,
    const float* __restrict__ b1, const float* __restrict__ W2,
    const float* __restrict__ b2, float* __restrict__ qw,
    float* __restrict__ kwT, float* __restrict__ biasT)
{
    __shared__ float inpS[ROWS * HID];   // 24 KB; first 4 KB reused as xs[8][128]
    __shared__ float ps[ROWS][N1];       // 4 KB: upper-K-half partials
    __shared__ float kT[HS][9];          // kwT transpose staging (+1 pad)

    const int tid = threadIdx.x;
    const int row0 = blockIdx.x * ROWS;
    const int b = row0 >> 9;
    const int m0 = row0 & 511;

    {   // stage inp tile (coalesced float4): 1536 float4, 512 threads x 3
        const float4* src = (const float4*)(inp + (size_t)row0 * HID);
        float4* dst = (float4*)inpS;
#pragma unroll
        for (int i = 0; i < 3; ++i)
            dst[tid + i * 512] = src[tid + i * 512];
    }
    __syncthreads();

    const int kh = tid >> 8;            // K-half (wave-uniform)
    const int t  = tid & 255;
    const int c2 = t & 63;              // col pair: cols 2c2, 2c2+1
    const int rg = t >> 6;              // row group: rows 2rg, 2rg+1 (wave-uniform)
    const float* a0p = inpS + (2 * rg) * HID + kh * KHALF;
    const float* a1p = a0p + HID;
    const float* wp  = W1 + (size_t)(kh * KHALF) * N1 + c2 * 2;

    float acc00 = 0.f, acc01 = 0.f, acc10 = 0.f, acc11 = 0.f;
    float2 w0[8], w1[8], w2[8];
    LOADW(w0, 0);
    LOADW(w1, 8);

    for (int kb = 0; kb < KHALF; kb += 24) {
        LOADW(w2, kb + 16);
        FMA8(w0, kb);
        if (kb + 24 < KHALF) LOADW(w0, kb + 24);
        FMA8(w1, kb + 8);
        if (kb + 32 < KHALF) LOADW(w1, kb + 32);
        FMA8(w2, kb + 16);
    }

    if (kh == 1) {   // upper half -> LDS partials
        *(float2*)&ps[2 * rg][2 * c2]     = make_float2(acc00, acc01);
        *(float2*)&ps[2 * rg + 1][2 * c2] = make_float2(acc10, acc11);
    }
    __syncthreads();

    float* xs = inpS;                   // overlay xs[8][128]
    if (kh == 0) {                      // merge + b1 -> xs
        float2 bb = *(const float2*)(b1 + c2 * 2);
        float2 p0 = *(const float2*)&ps[2 * rg][2 * c2];
        float2 p1 = *(const float2*)&ps[2 * rg + 1][2 * c2];
        *(float2*)(xs + (2 * rg) * N1 + c2 * 2) =
            make_float2(acc00 + p0.x + bb.x, acc01 + p0.y + bb.y);
        *(float2*)(xs + (2 * rg + 1) * N1 + c2 * 2) =
            make_float2(acc10 + p1.x + bb.x, acc11 + p1.y + bb.y);
    }
    __syncthreads();

    if (tid < 256) {   // RoPE: thread = (row r, pair j)
        const int r = tid >> 5, j = tid & 31;
        const int m = m0 + r;
        const float C = 0.4152410118609203f;      // log2(10000)/32
        float invf = exp2f(-(float)j * C);        // 10000^(-j/32)
        float ang = (float)m * invf;
        float sv, cv;
        sincosf(ang, &sv, &cv);
        float4 xv = *(const float4*)(xs + r * N1 + 4 * j);
        float rq0 = xv.x * cv - xv.z * sv;        // q pair = x[4j], x[4j+2]
        float rq1 = xv.x * sv + xv.z * cv;
        float rk0 = xv.y * cv - xv.w * sv;        // k pair = x[4j+1], x[4j+3]
        float rk1 = xv.y * sv + xv.w * cv;
        *(float2*)(qw + (size_t)(b * SEQ + m) * HS + 2 * j) = make_float2(rq0, rq1);
        kT[2 * j][r]     = rk0;
        kT[2 * j + 1][r] = rk1;
    } else if (tid < 256 + ROWS * N2) {  // bias = (x@W2 + b2) * 0.5, c-major
        int t2 = tid - 256;
        int r = t2 / N2, c = t2 - r * N2;
        const float* xr = xs + r * N1;
        float dot = b2[c];
#pragma unroll 8
        for (int k = 0; k < N1; ++k)
            dot = fmaf(xr[k], W2[k * N2 + c], dot);
        biasT[(size_t)(b * N2 + c) * SEQ + m0 + r] = dot * 0.5f;
    }
    __syncthreads();

    if (tid < 256) {   // kwT writeout from LDS transpose
        int d = tid >> 2, q = tid & 3;
        float2 v = *(const float2*)&kT[d][2 * q];
        *(float2*)(kwT + (size_t)(b * HS + d) * SEQ + m0 + 2 * q) = v;
    }
}

// Kernel 2: per block = (b, 8 m-rows) x 512 n. 256 threads, 2 n's each -> float2 stores.
__global__ __launch_bounds__(256) void k2_out(
    const float* __restrict__ qw, const float* __restrict__ kwT,
    const float* __restrict__ biasT, const int* __restrict__ am,
    float* __restrict__ out)
{
    __shared__ float q_lds[8][HS];
    __shared__ float bo[8][HEADS];
    __shared__ int amm[8];

    const int tid = threadIdx.x;
    const int b = blockIdx.x >> 6;
    const int m0 = (blockIdx.x & 63) * 8;

#pragma unroll
    for (int i = 0; i < 2; ++i) {
        int idx = tid + i * 256;
        q_lds[idx >> 6][idx & 63] = qw[(size_t)(b * SEQ + m0) * HS + idx];
    }
    if (tid < 96) {
        int r = tid / 12, h = tid - r * 12;
        bo[r][h] = biasT[(size_t)(b * N2 + 2 * h + 1) * SEQ + m0 + r];
    }
    if (tid < 8) amm[tid] = am[b * SEQ + m0 + tid];
    __syncthreads();

    const int n0 = tid * 2;
    float qk0[8] = {0, 0, 0, 0, 0, 0, 0, 0};
    float qk1[8] = {0, 0, 0, 0, 0, 0, 0, 0};

#pragma unroll
    for (int dc = 0; dc < 2; ++dc) {
        float2 kn[32];
#pragma unroll
        for (int d = 0; d < 32; ++d)
            kn[d] = *(const float2*)&kwT[(size_t)(b * HS + dc * 32 + d) * SEQ + n0];
#pragma unroll
        for (int r = 0; r < 8; ++r) {
#pragma unroll
            for (int d4 = 0; d4 < 8; ++d4) {
                float4 qv = *(const float4*)&q_lds[r][dc * 32 + d4 * 4];
                qk0[r] = fmaf(qv.x, kn[d4 * 4 + 0].x, qk0[r]);
                qk0[r] = fmaf(qv.y, kn[d4 * 4 + 1].x, qk0[r]);
                qk0[r] = fmaf(qv.z, kn[d4 * 4 + 2].x, qk0[r]);
                qk0[r] = fmaf(qv.w, kn[d4 * 4 + 3].x, qk0[r]);
                qk1[r] = fmaf(qv.x, kn[d4 * 4 + 0].y, qk1[r]);
                qk1[r] = fmaf(qv.y, kn[d4 * 4 + 1].y, qk1[r]);
                qk1[r] = fmaf(qv.z, kn[d4 * 4 + 2].y, qk1[r]);
                qk1[r] = fmaf(qv.w, kn[d4 * 4 + 3].y, qk1[r]);
            }
        }
    }

    const int amn0 = am[b * SEQ + n0];
    const int amn1 = am[b * SEQ + n0 + 1];
    float pen0[8], pen1[8];
    float2 mo[8];
#pragma unroll
    for (int r = 0; r < 8; ++r) {
        int m = m0 + r;
        float msk0 = (1.0f - (float)(amn0 * amm[r])) * INFV;
        float msk1 = (1.0f - (float)(amn1 * amm[r])) * INFV;
        pen0[r] = msk0 + ((n0 < m) ? INFV : 0.0f);
        pen1[r] = msk1 + ((n0 + 1 < m) ? INFV : 0.0f);
        bool b0 = (amn0 * amm[r] != 1) || (n0 < m);
        bool b1m = (amn1 * amm[r] != 1) || (n0 + 1 < m);
        mo[r].x = b0 ? 1.0f : 0.0f;
        mo[r].y = b1m ? 1.0f : 0.0f;
    }

    float2 be[HEADS];
#pragma unroll
    for (int h = 0; h < HEADS; ++h)
        be[h] = *(const float2*)&biasT[(size_t)(b * N2 + 2 * h) * SEQ + n0];

    const size_t obase = (size_t)b * HEADS * SEQ * SEQ + n0;
#pragma unroll
    for (int h = 0; h < HEADS; ++h) {
#pragma unroll
        for (int r = 0; r < 8; ++r) {
            float2 v;
            v.x = fmaf(qk0[r], 0.125f, be[h].x + bo[r][h]) - pen0[r];
            v.y = fmaf(qk1[r], 0.125f, be[h].y + bo[r][h]) - pen1[r];
            *(float2*)&out[obase + ((size_t)h * SEQ + m0 + r) * SEQ] = v;
        }
    }
    const size_t mbase = (size_t)BSZ * HEADS * SEQ * SEQ
                       + ((size_t)b * SEQ + m0) * SEQ + n0;
#pragma unroll
    for (int r = 0; r < 8; ++r)
        *(float2*)&out[mbase + (size_t)r * SEQ] = mo[r];
}

extern "C" void kernel_launch(void* const* d_in, const int* in_sizes, int n_in,
                              void* d_out, int out_size, void* d_ws, size_t ws_size,
                              hipStream_t stream) {
    const float* inp = (const float*)d_in[0];
    const int*   am  = (const int*)d_in[1];
    const float* W1  = (const float*)d_in[2];
    const float* b1  = (const float*)d_in[3];
    const float* W2  = (const float*)d_in[4];
    const float* b2  = (const float*)d_in[5];

    float* ws    = (float*)d_ws;
    float* qw    = ws;                 // 8*512*64 = 262144 floats
    float* kwT   = ws + 262144;        // 8*64*512 = 262144 floats
    float* biasT = ws + 524288;        // 8*24*512 =  98304 floats

    float* out = (float*)d_out;

    hipLaunchKernelGGL(k1_proj, dim3(4096 / ROWS), dim3(512), 0, stream,
                       inp, W1, b1, W2, b2, qw, kwT, biasT);
    hipLaunchKernelGGL(k2_out, dim3(4096 / 8), dim3(256), 0, stream,
                       qw, kwT, biasT, am, out);
}

// Round 5
// 48.231 us; speedup vs baseline: 3.5787x; 1.6012x over previous
//
#include <hip/hip_runtime.h>

#define BSZ 8
#define SEQ 512
#define HID 768
#define N1 128
#define N2 24
#define HS 64
#define HEADS 12
#define INFV 10000.0f

typedef __attribute__((ext_vector_type(8))) short s8b;     // 8 bf16 (4 VGPR)
typedef __attribute__((ext_vector_type(4))) float f32x4;   // MFMA acc

__device__ __forceinline__ unsigned short f2bf(float f) {
    union { float f; unsigned int u; } c; c.f = f;
    unsigned int u = c.u;
    u += 0x7FFFu + ((u >> 16) & 1u);   // RNE
    return (unsigned short)(u >> 16);
}

// k0: W1 (768x128 f32) -> W1T (128x768 bf16): W1T[c][k] = bf16(W1[k][c])
__global__ __launch_bounds__(128) void k0_w1t(const float* __restrict__ W1,
                                              unsigned short* __restrict__ W1T) {
    const int c = threadIdx.x;            // 0..127
    const int k0 = blockIdx.x * 8;        // 96 blocks
    unsigned short v[8];
#pragma unroll
    for (int i = 0; i < 8; ++i)
        v[i] = f2bf(W1[(size_t)(k0 + i) * N1 + c]);   // coalesced across lanes
    unsigned short* dst = W1T + (size_t)c * HID + k0; // 16B/lane store
#pragma unroll
    for (int i = 0; i < 8; ++i) dst[i] = v[i];
}

// k1: 256 blocks x 512 thr. Block = 16 rows x 128 cols of x = inp@W1 + b1 via
// bf16 MFMA (A staged in LDS frag layout, B from L2-resident W1T).
// Fused epilogue: RoPE -> qw + kwT (LDS transpose), bias = (x@W2+b2)/2 -> biasT.
__global__ __launch_bounds__(512, 2) void k1_proj(
    const float* __restrict__ inp, const unsigned short* __restrict__ W1T,
    const float* __restrict__ b1, const float* __restrict__ W2,
    const float* __restrict__ b2, float* __restrict__ qw,
    float* __restrict__ kwT, float* __restrict__ biasT)
{
    __shared__ unsigned short aF[96 * 16 * 8];   // 24 KB: A bf16, slot = (k/8)*16+row, 8 bf16/slot
    __shared__ float xs[16 * N1];                // 8 KB
    __shared__ float kT[HS][17];                 // transpose staging (+1 pad)

    const int tid = threadIdx.x;
    const int row0 = blockIdx.x * 16;
    const int b = row0 >> 9;
    const int m0 = row0 & 511;

    {   // stage inp (fp32, coalesced float4) -> bf16 fragment layout in LDS
        const float4* src = (const float4*)(inp + (size_t)row0 * HID);
#pragma unroll
        for (int i = 0; i < 6; ++i) {
            int f4 = tid + i * 512;        // 0..3071
            int r = f4 / 192;              // row 0..15
            int c4 = f4 % 192;             // float4 index in row; k = c4*4
            float4 v = src[f4];
            int chunk = c4 >> 1;           // k/8
            int half = c4 & 1;
            ushort4 w;
            w.x = f2bf(v.x); w.y = f2bf(v.y); w.z = f2bf(v.z); w.w = f2bf(v.w);
            *(ushort4*)&aF[(chunk * 16 + r) * 8 + half * 4] = w;
        }
    }
    __syncthreads();

    const int wv = tid >> 6;      // wave 0..7 -> col tile
    const int ln = tid & 63;
    const int lr = ln & 15;       // A row / B col
    const int lg = ln >> 4;       // k-group
    const int c0 = wv * 16;

    // B frags: W1T row (c0+lr), k-window kc*32 + lg*8 (same k-bijection as A)
    const s8b* bp = (const s8b*)W1T + ((size_t)(c0 + lr) * 96 + lg);

    f32x4 acc = {0.f, 0.f, 0.f, 0.f};
#pragma unroll
    for (int kc = 0; kc < 24; ++kc) {
        s8b a = *(const s8b*)&aF[((kc * 4 + lg) * 16 + lr) * 8];
        s8b bw = bp[kc * 4];
        acc = __builtin_amdgcn_mfma_f32_16x16x32_bf16(a, bw, acc, 0, 0, 0);
    }

    {   // D: col = c0 + (lane&15), row = (lane>>4)*4 + reg  ->  xs + b1
        float b1v = b1[c0 + lr];
#pragma unroll
        for (int g = 0; g < 4; ++g)
            xs[(lg * 4 + g) * N1 + c0 + lr] = acc[g] + b1v;
    }
    __syncthreads();

    {   // RoPE: 512 thr = 16 rows x 32 pairs
        const int r = tid >> 5, j = tid & 31;
        const int m = m0 + r;
        const float C = 0.4152410118609203f;      // log2(10000)/32
        float invf = exp2f(-(float)j * C);        // 10000^(-j/32)
        float ang = (float)m * invf;
        float sv, cv;
        sincosf(ang, &sv, &cv);
        float4 xv = *(const float4*)&xs[r * N1 + 4 * j];
        float rq0 = xv.x * cv - xv.z * sv;        // q pair = x[4j], x[4j+2]
        float rq1 = xv.x * sv + xv.z * cv;
        float rk0 = xv.y * cv - xv.w * sv;        // k pair = x[4j+1], x[4j+3]
        float rk1 = xv.y * sv + xv.w * cv;
        *(float2*)(qw + (size_t)(b * SEQ + m) * HS + 2 * j) = make_float2(rq0, rq1);
        kT[2 * j][r]     = rk0;
        kT[2 * j + 1][r] = rk1;
    }
    if (tid < 16 * N2) {   // bias = (x@W2 + b2) * 0.5, c-major
        int r = tid / N2, c = tid - r * N2;
        const float* xr = &xs[r * N1];
        float dot = b2[c];
#pragma unroll 8
        for (int k = 0; k < N1; ++k)
            dot = fmaf(xr[k], W2[k * N2 + c], dot);
        biasT[(size_t)(b * N2 + c) * SEQ + m0 + r] = dot * 0.5f;
    }
    __syncthreads();

    {   // kwT writeout: 64 d-rows x 8 m-pairs
        int d = tid >> 3, q = tid & 7;
        float2 v = *(const float2*)&kT[d][2 * q];
        *(float2*)(kwT + (size_t)(b * HS + d) * SEQ + m0 + 2 * q) = v;
    }
}

// Kernel 2: per block = (b, 8 m-rows) x 512 n. 256 threads, 2 n's each -> float2 stores.
__global__ __launch_bounds__(256) void k2_out(
    const float* __restrict__ qw, const float* __restrict__ kwT,
    const float* __restrict__ biasT, const int* __restrict__ am,
    float* __restrict__ out)
{
    __shared__ float q_lds[8][HS];
    __shared__ float bo[8][HEADS];
    __shared__ int amm[8];

    const int tid = threadIdx.x;
    const int b = blockIdx.x >> 6;
    const int m0 = (blockIdx.x & 63) * 8;

#pragma unroll
    for (int i = 0; i < 2; ++i) {
        int idx = tid + i * 256;
        q_lds[idx >> 6][idx & 63] = qw[(size_t)(b * SEQ + m0) * HS + idx];
    }
    if (tid < 96) {
        int r = tid / 12, h = tid - r * 12;
        bo[r][h] = biasT[(size_t)(b * N2 + 2 * h + 1) * SEQ + m0 + r];
    }
    if (tid < 8) amm[tid] = am[b * SEQ + m0 + tid];
    __syncthreads();

    const int n0 = tid * 2;
    float qk0[8] = {0, 0, 0, 0, 0, 0, 0, 0};
    float qk1[8] = {0, 0, 0, 0, 0, 0, 0, 0};

#pragma unroll
    for (int dc = 0; dc < 2; ++dc) {
        float2 kn[32];
#pragma unroll
        for (int d = 0; d < 32; ++d)
            kn[d] = *(const float2*)&kwT[(size_t)(b * HS + dc * 32 + d) * SEQ + n0];
#pragma unroll
        for (int r = 0; r < 8; ++r) {
#pragma unroll
            for (int d4 = 0; d4 < 8; ++d4) {
                float4 qv = *(const float4*)&q_lds[r][dc * 32 + d4 * 4];
                qk0[r] = fmaf(qv.x, kn[d4 * 4 + 0].x, qk0[r]);
                qk0[r] = fmaf(qv.y, kn[d4 * 4 + 1].x, qk0[r]);
                qk0[r] = fmaf(qv.z, kn[d4 * 4 + 2].x, qk0[r]);
                qk0[r] = fmaf(qv.w, kn[d4 * 4 + 3].x, qk0[r]);
                qk1[r] = fmaf(qv.x, kn[d4 * 4 + 0].y, qk1[r]);
                qk1[r] = fmaf(qv.y, kn[d4 * 4 + 1].y, qk1[r]);
                qk1[r] = fmaf(qv.z, kn[d4 * 4 + 2].y, qk1[r]);
                qk1[r] = fmaf(qv.w, kn[d4 * 4 + 3].y, qk1[r]);
            }
        }
    }

    const int amn0 = am[b * SEQ + n0];
    const int amn1 = am[b * SEQ + n0 + 1];
    float pen0[8], pen1[8];
    float2 mo[8];
#pragma unroll
    for (int r = 0; r < 8; ++r) {
        int m = m0 + r;
        float msk0 = (1.0f - (float)(amn0 * amm[r])) * INFV;
        float msk1 = (1.0f - (float)(amn1 * amm[r])) * INFV;
        pen0[r] = msk0 + ((n0 < m) ? INFV : 0.0f);
        pen1[r] = msk1 + ((n0 + 1 < m) ? INFV : 0.0f);
        bool b0 = (amn0 * amm[r] != 1) || (n0 < m);
        bool b1m = (amn1 * amm[r] != 1) || (n0 + 1 < m);
        mo[r].x = b0 ? 1.0f : 0.0f;
        mo[r].y = b1m ? 1.0f : 0.0f;
    }

    float2 be[HEADS];
#pragma unroll
    for (int h = 0; h < HEADS; ++h)
        be[h] = *(const float2*)&biasT[(size_t)(b * N2 + 2 * h) * SEQ + n0];

    const size_t obase = (size_t)b * HEADS * SEQ * SEQ + n0;
#pragma unroll
    for (int h = 0; h < HEADS; ++h) {
#pragma unroll
        for (int r = 0; r < 8; ++r) {
            float2 v;
            v.x = fmaf(qk0[r], 0.125f, be[h].x + bo[r][h]) - pen0[r];
            v.y = fmaf(qk1[r], 0.125f, be[h].y + bo[r][h]) - pen1[r];
            *(float2*)&out[obase + ((size_t)h * SEQ + m0 + r) * SEQ] = v;
        }
    }
    const size_t mbase = (size_t)BSZ * HEADS * SEQ * SEQ
                       + ((size_t)b * SEQ + m0) * SEQ + n0;
#pragma unroll
    for (int r = 0; r < 8; ++r)
        *(float2*)&out[mbase + (size_t)r * SEQ] = mo[r];
}

extern "C" void kernel_launch(void* const* d_in, const int* in_sizes, int n_in,
                              void* d_out, int out_size, void* d_ws, size_t ws_size,
                              hipStream_t stream) {
    const float* inp = (const float*)d_in[0];
    const int*   am  = (const int*)d_in[1];
    const float* W1  = (const float*)d_in[2];
    const float* b1  = (const float*)d_in[3];
    const float* W2  = (const float*)d_in[4];
    const float* b2  = (const float*)d_in[5];

    float* ws    = (float*)d_ws;
    float* qw    = ws;                 // 8*512*64 = 262144 floats
    float* kwT   = ws + 262144;        // 8*64*512 = 262144 floats
    float* biasT = ws + 524288;        // 8*24*512 =  98304 floats
    unsigned short* W1T = (unsigned short*)(ws + 622592);  // 128*768 bf16 = 192 KB

    float* out = (float*)d_out;

    hipLaunchKernelGGL(k0_w1t, dim3(96), dim3(128), 0, stream, W1, W1T);
    hipLaunchKernelGGL(k1_proj, dim3(4096 / 16), dim3(512), 0, stream,
                       inp, W1T, b1, W2, b2, qw, kwT, biasT);
    hipLaunchKernelGGL(k2_out, dim3(4096 / 8), dim3(256), 0, stream,
                       qw, kwT, biasT, am, out);
}